// Round 5
// baseline (297.132 us; speedup 1.0000x reference)
//
#include <hip/hip_runtime.h>
#include <cstdint>

// Problem constants: view1 (B=8, C=4, H=256, W=256) fp32, F 3x3 fp32.
constexpr int Hh = 256, Ww = 256, BCc = 32;   // BC = B*C = 32 channels

typedef _Float16 half2v __attribute__((ext_vector_type(2)));
typedef uint32_t uint4v __attribute__((ext_vector_type(4)));

static __device__ inline float fdot2acc(half2v a, half2v b, float c) {
#if __has_builtin(__builtin_amdgcn_fdot2)
    return __builtin_amdgcn_fdot2(a, b, c, false);
#else
    return fmaf((float)a.x, (float)b.x, fmaf((float)a.y, (float)b.y, c));
#endif
}

// ---------------------------------------------------------------------------
// Pack view1 (ch,H,W) f32 -> Tpair[r][u][ch][rr] fp16, rr in {0,1} = rows r,
// r+1 (row 256 zero-padded). One block per r; LDS-staged so stores are linear.
// Word index in Tp: (r*256+u)*32 + ch  (each word = half2 (row r, row r+1)).
// ---------------------------------------------------------------------------
__global__ __launch_bounds__(256) void fume_pack(const float* __restrict__ in,
                                                 uint32_t* __restrict__ Tp) {
    __shared__ uint32_t lds[256 * 33];          // [u][ch], stride 33
    const int u = threadIdx.x;
    const int r = blockIdx.x;
    const bool has1 = (r < Hh - 1);
#pragma unroll
    for (int ch = 0; ch < BCc; ++ch) {          // coalesced per channel plane
        float a = in[ch * (Hh * Ww) + r * Ww + u];
        float b = has1 ? in[ch * (Hh * Ww) + (r + 1) * Ww + u] : 0.f;
        half2v p; p.x = (_Float16)a; p.y = (_Float16)b;
        uint32_t w; __builtin_memcpy(&w, &p, 4);
        lds[u * 33 + ch] = w;
    }
    __syncthreads();
    uint32_t* dst = Tp + (size_t)r * (Ww * BCc);
#pragma unroll
    for (int j = 0; j < 32; ++j) {              // linear coalesced stores
        int o = j * 256 + threadIdx.x;          // 0..8191
        int uu = o >> 5, ch = o & 31;
        dst[o] = lds[uu * 33 + ch];
    }
}

// ---------------------------------------------------------------------------
// Main. Lane = ALL 32 channels of one pixel for one u-chunk (amortizes the
// per-step line math over 32 dot2s). Wave = 16 x-pixels x 4 u-chunks; block =
// 4 waves at consecutive y. Chunk partials combined by shfl reduce-scatter.
// ---------------------------------------------------------------------------
template <bool USE_T>
__global__ __launch_bounds__(256, 4) void fume_main(const void* __restrict__ srcv,
                                                    const float* __restrict__ Fm,
                                                    float* __restrict__ out) {
    const int t     = threadIdx.x;
    const int chunk = t & 3;                     // u-chunk 0..3
    const int pxx   = (t >> 2) & 15;             // x within 16-wide strip
    const int wv    = t >> 6;                    // y within block
    const int x = ((int)blockIdx.x & 15) * 16 + pxx;
    const int y = ((int)blockIdx.x >> 4) * 4 + wv;
    const int pix = y * Ww + x;

    // Epipolar line l1 = F^T x2, normalized (reference op order).
    float xf = (float)x, yf = (float)y;
    float a = Fm[0] * xf + Fm[3] * yf + Fm[6];
    float b = Fm[1] * xf + Fm[4] * yf + Fm[7];
    float c = Fm[2] * xf + Fm[5] * yf + Fm[8];
    float n = sqrtf(a * a + b * b) + 1e-12f;
    a /= n; b /= n; c /= n;

    float acc[BCc];
#pragma unroll
    for (int k = 0; k < BCc; ++k) acc[k] = 0.f;

    int u_lo = 0, u_hi = -1;
    float alpha = 0.f, beta = 0.f;
    if (fabsf(b) > 1e-6f) {                      // 'ok' mask
        alpha = -a / b;                          // v(u) = alpha*u + beta
        beta  = -c / b;
        u_lo = 0; u_hi = Ww - 1;
        // Outer clip: contribution exactly 0 unless v in (-1, 256); per-step
        // masks make boundary rounding harmless (oob steps get w0=w1=0).
        if (fabsf(alpha) > 1e-12f) {
            float inv = 1.f / alpha;
            float t0 = (-1.f  - beta) * inv, t1 = (256.f - beta) * inv;
            int lo = (int)floorf(fminf(t0, t1)); // cvt saturates on overflow
            int hi = (int)ceilf (fmaxf(t0, t1));
            u_lo = lo > 0 ? lo : 0;
            u_hi = hi < (Ww - 1) ? hi : (Ww - 1);
        } else if (beta <= -1.f || beta >= 256.f) {
            u_hi = -1;
        }
    }

    // This lane's quarter of the range.
    int len = u_hi - u_lo + 1;                   // 0..256
    int us = u_lo + ((len * chunk) >> 2);
    int ue = u_lo + ((len * (chunk + 1)) >> 2) - 1;

    const uint32_t* base = (const uint32_t*)srcv;
    const float*    srcF = (const float*)srcv;

    for (int u = us; u <= ue; ++u) {
        float v  = fmaf(alpha, (float)u, beta);
        float rf = floorf(v);
        float f  = v - rf;
        int   ri = (int)rf;
        int   rb = ri < 0 ? 0 : (ri > Hh - 1 ? Hh - 1 : ri);
        bool inb = ((unsigned)ri < (unsigned)Hh);
        // Weights vs cell rb = rows (rb, rb+1). ri==-1 -> f*row0; ri==255 ok
        // because Tpair[255][..][1] is zero-padded.
        float w0 = inb ? (1.f - f) : (ri == -1 ? f : 0.f);
        float w1 = inb ? f : 0.f;
        if constexpr (USE_T) {
            half2v wp; wp.x = (_Float16)w0; wp.y = (_Float16)w1;
            const uint4v* cell = (const uint4v*)(base + (((rb << 8) + u) << 5));
#pragma unroll
            for (int j = 0; j < 8; ++j) {
                uint4v cj = cell[j];             // 8x dwordx4 = full 128B cell
#pragma unroll
                for (int i = 0; i < 4; ++i) {
                    uint32_t w = cj[i];
                    half2v s; __builtin_memcpy(&s, &w, 4);
                    acc[j * 4 + i] = fdot2acc(wp, s, acc[j * 4 + i]);
                }
            }
        } else {
#pragma unroll
            for (int k = 0; k < BCc; ++k) {
                float s0 = srcF[(size_t)k * (Hh * Ww) + rb * Ww + u];
                float s1 = (rb < Hh - 1)
                             ? srcF[(size_t)k * (Hh * Ww) + (rb + 1) * Ww + u]
                             : 0.f;
                acc[k] = fmaf(w0, s0, fmaf(w1, s1, acc[k]));
            }
        }
    }

    // Reduce-scatter over the 4 chunk lanes (lane^1 = chunk bit0, ^2 = bit1).
    const int b0 = chunk & 1, b1 = (chunk >> 1) & 1;
    float r16[16];
#pragma unroll
    for (int k = 0; k < 16; ++k) {
        float keep = b0 ? acc[k + 16] : acc[k];
        float send = b0 ? acc[k]      : acc[k + 16];
        r16[k] = keep + __shfl_xor(send, 1, 64);
    }
    float r8[8];
#pragma unroll
    for (int k = 0; k < 8; ++k) {
        float keep = b1 ? r16[k + 8] : r16[k];
        float send = b1 ? r16[k]     : r16[k + 8];
        r8[k] = keep + __shfl_xor(send, 2, 64);
    }
    // Channel slice held by this chunk lane: c=0->0, 1->16, 2->8, 3->24.
    const int ch0 = ((chunk & 1) << 4) | ((chunk & 2) << 2);
#pragma unroll
    for (int k = 0; k < 8; ++k)
        out[(size_t)(ch0 + k) * (Hh * Ww) + pix] = r8[k];
}

extern "C" void kernel_launch(void* const* d_in, const int* in_sizes, int n_in,
                              void* d_out, int out_size, void* d_ws, size_t ws_size,
                              hipStream_t stream) {
    const float* view1 = (const float*)d_in[0];   // 8*4*256*256 fp32
    const float* Fm    = (const float*)d_in[1];   // 9 fp32, row-major 3x3
    float* out = (float*)d_out;

    constexpr size_t t_bytes = (size_t)Hh * Ww * BCc * 4;   // 8 MiB fp16 pairs
    constexpr int n_blocks = (Hh * Ww * 4) / 256;           // 1024
    if (ws_size >= t_bytes) {
        uint32_t* Tp = (uint32_t*)d_ws;
        fume_pack<<<Hh, 256, 0, stream>>>(view1, Tp);
        fume_main<true><<<n_blocks, 256, 0, stream>>>(Tp, Fm, out);
    } else {
        fume_main<false><<<n_blocks, 256, 0, stream>>>(view1, Fm, out);
    }
}

// Round 7
// 133.391 us; speedup vs baseline: 2.2275x; 2.2275x over previous
//
#include <hip/hip_runtime.h>
#include <cstdint>

// Problem constants: view1 (B=8, C=4, H=256, W=256) fp32, F 3x3 fp32.
constexpr int Hh = 256, Ww = 256, BCc = 32;   // BC = B*C = 32 channels

typedef _Float16 half2v __attribute__((ext_vector_type(2)));
typedef __fp16   fp16x2 __attribute__((ext_vector_type(2)));
typedef uint32_t uint4v __attribute__((ext_vector_type(4)));

static __device__ inline float fdot2acc(half2v a, half2v b, float c) {
#if __has_builtin(__builtin_amdgcn_fdot2)
    return __builtin_amdgcn_fdot2(a, b, c, false);
#else
    return fmaf((float)a.x, (float)b.x, fmaf((float)a.y, (float)b.y, c));
#endif
}
static __device__ inline half2v pack2(float a, float b) {
#if __has_builtin(__builtin_amdgcn_cvt_pkrtz)
    fp16x2 r = __builtin_amdgcn_cvt_pkrtz(a, b);   // one v_cvt_pkrtz_f16_f32
    return __builtin_bit_cast(half2v, r);
#else
    half2v r; r.x = (_Float16)a; r.y = (_Float16)b; return r;
#endif
}

// ---------------------------------------------------------------------------
// Pack view1 (ch,H,W) f32 -> Tpair[r][u][ch] = half2(row r, row r+1), row 256
// zero-padded. One block per r; LDS-staged so global stores are linear.
// ---------------------------------------------------------------------------
__global__ __launch_bounds__(256) void fume_pack(const float* __restrict__ in,
                                                 uint32_t* __restrict__ Tp) {
    __shared__ uint32_t lds[256 * 33];          // [u][ch], stride 33
    const int u = threadIdx.x;
    const int r = blockIdx.x;
    const bool has1 = (r < Hh - 1);
#pragma unroll
    for (int ch = 0; ch < BCc; ++ch) {          // coalesced per channel plane
        float a = in[ch * (Hh * Ww) + r * Ww + u];
        float b = has1 ? in[ch * (Hh * Ww) + (r + 1) * Ww + u] : 0.f;
        half2v p; p.x = (_Float16)a; p.y = (_Float16)b;
        uint32_t w; __builtin_memcpy(&w, &p, 4);
        lds[u * 33 + ch] = w;
    }
    __syncthreads();
    uint32_t* dst = Tp + (size_t)r * (Ww * BCc);
#pragma unroll
    for (int j = 0; j < 32; ++j) {              // linear coalesced stores
        int o = j * 256 + threadIdx.x;          // 0..8191
        int uu = o >> 5, ch = o & 31;
        dst[o] = lds[uu * 33 + ch];
    }
}

// ---------------------------------------------------------------------------
// Main. R4 lane map (wave = 16-px x-strip x 4 channel-parts; all 4 parts of a
// pixel hit the same 128B cell -> intra-instruction dedup). New vs R4:
//  * interior/edge split: interior v in [0,256) -> mask-free body (~18 issue)
//  * per-WAVE u-half split (both halves keep the 16-px front); the two
//    half-waves of a strip share a block and combine via LDS at the end.
// ---------------------------------------------------------------------------
template <bool USE_T>
__global__ __launch_bounds__(256, 8) void fume_main(const void* __restrict__ srcv,
                                                    const float* __restrict__ Fm,
                                                    float* __restrict__ out) {
    __shared__ float red[2][16][32];             // 4KB; swizzled below
    const int t    = threadIdx.x;
    const int lane = t & 63;
    const int wv   = t >> 6;                     // 0..3
    const int part = lane & 3;                   // channel part, ch0 = part*8
    const int pxx  = lane >> 2;                  // 0..15 in x-strip
    const int uh   = wv & 1;                     // u-half of this wave
    const int ly   = wv >> 1;                    // y within block (0..1)
    const int x = ((int)blockIdx.x & 15) * 16 + pxx;
    const int y = ((int)blockIdx.x >> 4) * 2 + ly;
    const int pix = y * Ww + x;

    // Epipolar line l1 = F^T x2, normalized (reference op order).
    float xf = (float)x, yf = (float)y;
    float a = Fm[0] * xf + Fm[3] * yf + Fm[6];
    float b = Fm[1] * xf + Fm[4] * yf + Fm[7];
    float c = Fm[2] * xf + Fm[5] * yf + Fm[8];
    float n = sqrtf(a * a + b * b) + 1e-12f;
    a /= n; b /= n; c /= n;

    float acc[8];
#pragma unroll
    for (int k = 0; k < 8; ++k) acc[k] = 0.f;

    int u_lo = 0, u_hi = -1;
    float alpha = 0.f, beta = 0.f;
    if (fabsf(b) > 1e-6f) {                      // 'ok' mask
        alpha = -a / b;                          // v(u) = alpha*u + beta
        beta  = -c / b;
        u_lo = 0; u_hi = Ww - 1;
        // Outer clip: contribution exactly 0 unless v in (-1, 256).
        if (fabsf(alpha) > 1e-12f) {
            float inv = 1.f / alpha;
            float t0 = (-1.f  - beta) * inv, t1 = (256.f - beta) * inv;
            int lo = (int)floorf(fminf(t0, t1)); // cvt saturates on overflow
            int hi = (int)ceilf (fmaxf(t0, t1));
            u_lo = lo > 0 ? lo : 0;
            u_hi = hi < (Ww - 1) ? hi : (Ww - 1);
        } else if (beta <= -1.f || beta >= 256.f) {
            u_hi = -1;
        }
    }

    // Interior: v in [0,256) -> ri in [0,255], no masks/clamps (row-256 pad).
    int i_lo = u_hi + 1, i_hi = u_hi;            // default: empty
    if (u_hi >= u_lo) {
        if (fabsf(alpha) > 1e-12f) {
            float inv = 1.f / alpha;
            float s0 = (0.f - beta) * inv, s1 = (256.f - beta) * inv;
            i_lo = (int)ceilf (fminf(s0, s1));
            i_hi = (int)floorf(fmaxf(s0, s1));
        } else { i_lo = u_lo; i_hi = u_hi; }
        i_lo = i_lo > u_lo ? i_lo : u_lo;
        i_hi = i_hi < u_hi ? i_hi : u_hi;
        // verify-adjust with the exact predicate (v monotone in u)
        while (i_lo <= i_hi) {
            float vv = fmaf(alpha, (float)i_lo, beta);
            if (vv >= 0.f && vv < 256.f) break; ++i_lo;
        }
        while (i_lo <= i_hi) {
            float vv = fmaf(alpha, (float)i_hi, beta);
            if (vv >= 0.f && vv < 256.f) break; --i_hi;
        }
        if (i_lo > i_hi) { i_lo = u_hi + 1; i_hi = u_hi; }
    }

    // This wave's u-half of [u_lo, u_hi].
    int mid = u_lo + ((u_hi - u_lo + 1) >> 1);
    int ws = uh ? mid  : u_lo;
    int we = uh ? u_hi : mid - 1;
    if (!USE_T) { ws = uh ? 1 : u_lo; we = uh ? 0 : u_hi; }  // fallback: h0 all
    int il = i_lo > ws ? i_lo : ws;
    int ih = i_hi < we ? i_hi : we;
    if (il > ih || !USE_T) { il = we + 1; ih = we; }         // no interior

    const uint32_t* base = (const uint32_t*)srcv + part * 8;
    const float*    srcF = (const float*)srcv;

    auto edge = [&](int u) {                     // fully masked step
        float v  = fmaf(alpha, (float)u, beta);
        float rf = floorf(v);
        float f  = v - rf;
        int   ri = (int)rf;
        int   rb = ri < 0 ? 0 : (ri > Hh - 1 ? Hh - 1 : ri);
        bool inb = ((unsigned)ri < (unsigned)Hh);
        float w0 = inb ? (1.f - f) : (ri == -1 ? f : 0.f);   // ri==255: pad
        float w1 = inb ? f : 0.f;
        if constexpr (USE_T) {
            half2v wp = pack2(w0, w1);
            const uint4v* cell = (const uint4v*)(base + (((rb << 8) + u) << 5));
            uint4v c0 = cell[0], c1 = cell[1];
#pragma unroll
            for (int i = 0; i < 4; ++i) {
                uint32_t w = c0[i]; half2v s; __builtin_memcpy(&s, &w, 4);
                acc[i] = fdot2acc(wp, s, acc[i]);
            }
#pragma unroll
            for (int i = 0; i < 4; ++i) {
                uint32_t w = c1[i]; half2v s; __builtin_memcpy(&s, &w, 4);
                acc[4 + i] = fdot2acc(wp, s, acc[4 + i]);
            }
        } else {
            int ch0 = part * 8;
#pragma unroll
            for (int k = 0; k < 8; ++k) {
                float s0 = srcF[(size_t)(ch0 + k) * (Hh * Ww) + rb * Ww + u];
                float s1 = (rb < Hh - 1)
                             ? srcF[(size_t)(ch0 + k) * (Hh * Ww) + (rb + 1) * Ww + u]
                             : 0.f;
                acc[k] = fmaf(w0, s0, fmaf(w1, s1, acc[k]));
            }
        }
    };

    for (int u = ws; u < il; ++u) edge(u);       // prologue (masked)

    if constexpr (USE_T) {
#pragma unroll 2
        for (int u = il; u <= ih; ++u) {         // hot: mask-free
            float v  = fmaf(alpha, (float)u, beta);
            float rf = floorf(v);
            float f  = v - rf;
            int   ri = (int)rf;                  // 0..255 (255 uses zero pad)
            half2v wp = pack2(1.f - f, f);
            const uint4v* cell = (const uint4v*)(base + (((ri << 8) + u) << 5));
            uint4v c0 = cell[0], c1 = cell[1];
#pragma unroll
            for (int i = 0; i < 4; ++i) {
                uint32_t w = c0[i]; half2v s; __builtin_memcpy(&s, &w, 4);
                acc[i] = fdot2acc(wp, s, acc[i]);
            }
#pragma unroll
            for (int i = 0; i < 4; ++i) {
                uint32_t w = c1[i]; half2v s; __builtin_memcpy(&s, &w, 4);
                acc[4 + i] = fdot2acc(wp, s, acc[4 + i]);
            }
        }
    }

    for (int u = ih + 1; u <= we; ++u) edge(u);  // epilogue (masked)

    // Combine the two u-half waves of this strip via LDS (swizzled: 2-way max).
    if (uh == 1) {
#pragma unroll
        for (int k = 0; k < 8; ++k)
            red[ly][pxx][(part * 8 + k + pxx) & 31] = acc[k];
    }
    __syncthreads();
    if (uh == 0) {
#pragma unroll
        for (int k = 0; k < 8; ++k) {
            int ch = part * 8 + k;
            float s = acc[k] + red[ly][pxx][(ch + pxx) & 31];
            out[(size_t)ch * (Hh * Ww) + pix] = s;
        }
    }
}

extern "C" void kernel_launch(void* const* d_in, const int* in_sizes, int n_in,
                              void* d_out, int out_size, void* d_ws, size_t ws_size,
                              hipStream_t stream) {
    const float* view1 = (const float*)d_in[0];   // 8*4*256*256 fp32
    const float* Fm    = (const float*)d_in[1];   // 9 fp32, row-major 3x3
    float* out = (float*)d_out;

    constexpr size_t t_bytes = (size_t)Hh * Ww * BCc * 4;   // 8 MiB fp16 pairs
    constexpr int n_blocks = 16 * (Hh / 2);                 // 2048
    if (ws_size >= t_bytes) {
        uint32_t* Tp = (uint32_t*)d_ws;
        fume_pack<<<Hh, 256, 0, stream>>>(view1, Tp);
        fume_main<true><<<n_blocks, 256, 0, stream>>>(Tp, Fm, out);
    } else {
        fume_main<false><<<n_blocks, 256, 0, stream>>>(view1, Fm, out);
    }
}